// Round 6
// baseline (134.223 us; speedup 1.0000x reference)
//
#include <hip/hip_runtime.h>
#include <math.h>

#define N 4096
#define D 256
#define NPOS 32768
#define TEMP 0.07f
#define INVT (1.0f / 0.07f)
#define BIGF 3.0e38f

#define RQ 5.5f                      // quantization range [-RQ, RQ]
#define QS (255.0f / (2.0f * RQ))    // f32 -> u8 scale
#define DEQ (2.0f * RQ / 255.0f)     // u8-units -> f32

#define NT 64                        // 64x64 tiles per dim
#define NTRI (NT * (NT + 1) / 2)     // 2080 triangle blocks
#define KC 16                        // u32 (k4) per D-chunk (=64 dims), 4 chunks

// workspace layout (floats):
// [0 .. 2*N*64)       pstat[r][c] float2 (pmin, psum), r=row, c=64-col-tile
// [2*N*64 .. +N)      t[r]
// [.. +1]             loss accumulator (float)
// [.. +1]             ticket counter (uint)
// [WS_XQ ..)          xqT: TRANSPOSED quant matrix, xqT[w][r], w=0..63, r=0..4095
#define WS_PSTAT 0
#define WS_T    (2 * N * NT)
#define WS_ACC  (2 * N * NT + N)
#define WS_CNT  (2 * N * NT + N + 1)
#define WS_XQ   (2 * N * NT + N + 4)   // 16B-aligned

typedef unsigned u32x4 __attribute__((ext_vector_type(4)));

__device__ __forceinline__ void sad_acc(unsigned a, unsigned b, unsigned& c) {
#if __has_builtin(__builtin_amdgcn_sad_u8)
    c = __builtin_amdgcn_sad_u8(a, b, c);
#else
    asm("v_sad_u8 %0, %1, %2, %0" : "+v"(c) : "v"(a), "v"(b));
#endif
}

// async global->LDS, 16B per lane. LDS dest = uniform base + lane*16.
__device__ __forceinline__ void g2l16(const unsigned* g, unsigned* l) {
    __builtin_amdgcn_global_load_lds(
        (const __attribute__((address_space(1))) unsigned*)g,
        (__attribute__((address_space(3))) unsigned*)l, 16, 0, 0);
}

__device__ __forceinline__ unsigned quant1(float v) {
    const float f = fminf(fmaxf((v + RQ) * QS, 0.0f), 255.0f);
    return (unsigned)__float2uint_rn(f);
}

// Quantize f32 -> packed u8 and store TRANSPOSED: xqT[w][r] (w=word 0..63,
// r=row). Transposed layout is what lets dist_tile_k stage with
// global_load_lds (linear LDS dest). LDS-transpose: both global sides
// coalesced; [64][65] padding -> conflict-free LDS.
__global__ __launch_bounds__(256)
void cvt_init_k(const float* __restrict__ x, unsigned* __restrict__ xqT,
                float* __restrict__ acc, unsigned* __restrict__ cnt) {
    __shared__ unsigned t[64][65];
    const int r0 = blockIdx.x * 64;     // 64 rows per block
    const int tid = threadIdx.x;
#pragma unroll
    for (int k = 0; k < 16; ++k) {
        const int idx = k * 256 + tid;  // 0..4095 over 64r x 64w
        const int rr = idx >> 6;
        const int w = idx & 63;
        const float4 v = ((const float4*)x)[(size_t)(r0 + rr) * 64 + w];
        t[w][rr] = quant1(v.x) | (quant1(v.y) << 8) |
                   (quant1(v.z) << 16) | (quant1(v.w) << 24);
    }
    __syncthreads();
#pragma unroll
    for (int k = 0; k < 16; ++k) {
        const int idx = k * 256 + tid;
        const int w = idx >> 6;         // wave-uniform per 64-lane group
        const int rr = idx & 63;        // lane -> consecutive r: coalesced
        xqT[(size_t)w * N + r0 + rr] = t[w][rr];
    }
    if (blockIdx.x == 0 && tid == 0) { *acc = 0.0f; *cnt = 0u; }
}

// 64 SADs of one k4: av rows ty*8..+7, bv cols tx*8..+7
#define SAD64(aL, aH, bL, bH)                                            \
    {                                                                    \
        const unsigned av[8] = {aL.x, aL.y, aL.z, aL.w,                  \
                                aH.x, aH.y, aH.z, aH.w};                 \
        const unsigned bv[8] = {bL.x, bL.y, bL.z, bL.w,                  \
                                bH.x, bH.y, bH.z, bH.w};                 \
        _Pragma("unroll") for (int i_ = 0; i_ < 8; ++i_)                 \
            _Pragma("unroll") for (int j_ = 0; j_ < 8; ++j_)             \
                sad_acc(av[i_], bv[j_], uacc[i_][j_]);                   \
    }

// 64x64 tile per block, ONE wave, 8x8 micro-tile (64 uacc regs).
// R5 POST-MORTEM: VGPR stuck at 88 across 3 pipelining attempts — the
// scheduler coalesces every C++-level pipeline back to
// {4 ds_read -> lgkmcnt(0) -> 64 SAD} per k4, exposing ~150cyc LDS latency
// per 256cyc SAD block (VALUBusy 41%); forced 4-wave co-residency (R5)
// didn't cover it. Fix: COMPILER-PROOF batch point. Per 4-k4 group: issue
// all 16 ds_read_b128, then an empty asm volatile with all 16 frags as
// "+v" operands — loads can't sink past it, SADs can't hoist above it.
// One lgkmcnt drain per 1024cyc of SADs instead of 4 per 1024.
// Register cost: 64 frag + 64 acc + addr ~= 145; waves_per_eu(1,2) keeps
// budget at 256 (no spill) and occupancy at the grid-given 2 waves/SIMD.
__global__ __launch_bounds__(64) __attribute__((amdgpu_waves_per_eu(1, 2)))
void dist_tile_k(const unsigned* __restrict__ xqT, float2* __restrict__ pstat) {
    // triangular decode: blockIdx.x -> (bm, bn), bm <= bn
    const int tt = blockIdx.x;
    const int u_ = (NTRI - 1) - tt;
    int r = (int)((sqrtf((float)(8 * u_ + 1)) - 1.0f) * 0.5f);
    while (r * (r + 1) / 2 > u_) --r;
    while ((r + 1) * (r + 2) / 2 <= u_) ++r;
    const int bm = (NT - 1) - r;                      // row tile
    const int bn = (NT - 1) - (u_ - r * (r + 1) / 2); // col tile
    const bool diag = (bm == bn);

    const int lane = threadIdx.x;   // 0..63
    const int tx = lane & 7;        // col group: cols tx*8 .. +7
    const int ty = lane >> 3;       // row group: rows ty*8 .. +7

    __shared__ unsigned As[2][KC][64];    // 4 KB x2
    __shared__ unsigned Bs[2][KC][64];    // 4 KB x2

    unsigned uacc[8][8];  // [i][j]: row ty*8+i, col tx*8+j
#pragma unroll
    for (int i = 0; i < 8; ++i)
#pragma unroll
        for (int j = 0; j < 8; ++j) uacc[i][j] = 0u;

    const int rowA0 = bm * 64;
    const int rowB0 = bn * 64;

    // per-lane global source: lane l covers k4 = q*4 + (l>>4), m = (l&15)*4..+3
    const int lrow = lane >> 4;
    const int lcol = (lane & 15) * 4;
    const unsigned* gA = xqT + (size_t)lrow * N + rowA0 + lcol;
    const unsigned* gB = xqT + (size_t)lrow * N + rowB0 + lcol;

    // prologue: stage chunk 0 -> buf 0
#pragma unroll
    for (int q = 0; q < 4; ++q) {
        g2l16(gA + (size_t)q * 4 * N, &As[0][q * 4][0]);
        g2l16(gB + (size_t)q * 4 * N, &Bs[0][q * 4][0]);
    }
    __syncthreads();   // vmcnt(0): chunk 0 resident

#pragma unroll 1
    for (int chk = 0; chk < 4; ++chk) {
        const int b = chk & 1;
        const unsigned* Ab = &As[b][0][0];
        const unsigned* Bb = &Bs[b][0][0];

        // issue next chunk's DMA into the other buffer; completes under SAD
        if (chk < 3) {
            const unsigned* pa = gA + (size_t)(chk + 1) * 16 * N;
            const unsigned* pb = gB + (size_t)(chk + 1) * 16 * N;
            unsigned* Ad = &As[b ^ 1][0][0];
            unsigned* Bd = &Bs[b ^ 1][0][0];
#pragma unroll
            for (int q = 0; q < 4; ++q) {
                g2l16(pa + (size_t)q * 4 * N, Ad + q * 256);
                g2l16(pb + (size_t)q * 4 * N, Bd + q * 256);
            }
        }

        // 4 batches of 4 k4-steps: 16 reads -> pin -> 256 SADs
#pragma unroll
        for (int kb = 0; kb < 4; ++kb) {
            const unsigned* Ak = Ab + kb * 4 * 64 + ty * 8;
            const unsigned* Bk = Bb + kb * 4 * 64 + tx * 8;
            u32x4 aL0 = *(const u32x4*)(Ak + 0 * 64);
            u32x4 aH0 = *(const u32x4*)(Ak + 0 * 64 + 4);
            u32x4 aL1 = *(const u32x4*)(Ak + 1 * 64);
            u32x4 aH1 = *(const u32x4*)(Ak + 1 * 64 + 4);
            u32x4 aL2 = *(const u32x4*)(Ak + 2 * 64);
            u32x4 aH2 = *(const u32x4*)(Ak + 2 * 64 + 4);
            u32x4 aL3 = *(const u32x4*)(Ak + 3 * 64);
            u32x4 aH3 = *(const u32x4*)(Ak + 3 * 64 + 4);
            u32x4 bL0 = *(const u32x4*)(Bk + 0 * 64);
            u32x4 bH0 = *(const u32x4*)(Bk + 0 * 64 + 4);
            u32x4 bL1 = *(const u32x4*)(Bk + 1 * 64);
            u32x4 bH1 = *(const u32x4*)(Bk + 1 * 64 + 4);
            u32x4 bL2 = *(const u32x4*)(Bk + 2 * 64);
            u32x4 bH2 = *(const u32x4*)(Bk + 2 * 64 + 4);
            u32x4 bL3 = *(const u32x4*)(Bk + 3 * 64);
            u32x4 bH3 = *(const u32x4*)(Bk + 3 * 64 + 4);
            // compiler-proof batch point: all 16 loads issued + drained here
            asm volatile(""
                         : "+v"(aL0), "+v"(aH0), "+v"(aL1), "+v"(aH1),
                           "+v"(aL2), "+v"(aH2), "+v"(aL3), "+v"(aH3),
                           "+v"(bL0), "+v"(bH0), "+v"(bL1), "+v"(bH1),
                           "+v"(bL2), "+v"(bH2), "+v"(bL3), "+v"(bH3));
            SAD64(aL0, aH0, bL0, bH0);
            SAD64(aL1, aH1, bL1, bH1);
            SAD64(aL2, aH2, bL2, bH2);
            SAD64(aL3, aH3, bL3, bH3);
        }
        // drains vmcnt (next chunk landed long ago) + lgkmcnt before the
        // buffer we just read gets overwritten.
        __syncthreads();
    }

    // dequantize to float
    float acc[8][8];
#pragma unroll
    for (int i = 0; i < 8; ++i)
#pragma unroll
        for (int j = 0; j < 8; ++j)
            acc[i][j] = (float)uacc[i][j] * DEQ;

    // diagonal exclusion: poison self-distance (min skips it, exp -> 0)
    if (diag) {
#pragma unroll
        for (int i = 0; i < 8; ++i)
#pragma unroll
            for (int j = 0; j < 8; ++j)
                if (ty * 8 + i == tx * 8 + j)   // iff ty==tx && i==j
                    acc[i][j] = BIGF;
    }

    // ---- row stats over all 64 cols: reduce across tx (shfl 1,2,4) ----
#pragma unroll
    for (int i = 0; i < 8; ++i) {
        float mn = BIGF;
#pragma unroll
        for (int j = 0; j < 8; ++j) mn = fminf(mn, acc[i][j]);
        mn = fminf(mn, __shfl_xor(mn, 1, 64));
        mn = fminf(mn, __shfl_xor(mn, 2, 64));
        mn = fminf(mn, __shfl_xor(mn, 4, 64));
        float s = 0.0f;
#pragma unroll
        for (int j = 0; j < 8; ++j)
            s += __expf((mn - acc[i][j]) * INVT);
        s += __shfl_xor(s, 1, 64);
        s += __shfl_xor(s, 2, 64);
        s += __shfl_xor(s, 4, 64);
        if (tx == 0)
            pstat[(size_t)(rowA0 + ty * 8 + i) * NT + bn] = make_float2(mn, s);
    }

    // ---- col stats (iff bm < bn): reduce across ty (shfl 8,16,32) ----
    if (!diag) {
#pragma unroll
        for (int j = 0; j < 8; ++j) {
            float mn = BIGF;
#pragma unroll
            for (int i = 0; i < 8; ++i) mn = fminf(mn, acc[i][j]);
            mn = fminf(mn, __shfl_xor(mn, 8, 64));
            mn = fminf(mn, __shfl_xor(mn, 16, 64));
            mn = fminf(mn, __shfl_xor(mn, 32, 64));
            float s = 0.0f;
#pragma unroll
            for (int i = 0; i < 8; ++i)
                s += __expf((mn - acc[i][j]) * INVT);
            s += __shfl_xor(s, 8, 64);
            s += __shfl_xor(s, 16, 64);
            s += __shfl_xor(s, 32, 64);
            if (ty == 0)
                pstat[(size_t)(rowB0 + tx * 8 + j) * NT + bm] =
                    make_float2(mn, s);
        }
    }
}

// One wave per row: coalesced float2 read of the 64 partials, shuffle reduce.
__global__ __launch_bounds__(256)
void row_stats_k(const float2* __restrict__ pstat, float* __restrict__ t) {
    const int r = blockIdx.x * 4 + (threadIdx.x >> 6);
    const int c = threadIdx.x & 63;
    const float2 p = pstat[(size_t)r * NT + c];
    float mn = p.x;
#pragma unroll
    for (int off = 32; off > 0; off >>= 1) mn = fminf(mn, __shfl_xor(mn, off, 64));
    float s = p.y * __expf((mn - p.x) * INVT);
#pragma unroll
    for (int off = 32; off > 0; off >>= 1) s += __shfl_xor(s, off, 64);
    if (c == 0) t[r] = TEMP * __logf(s) - mn;
}

// 1024 blocks x 4 waves x 8 pairs; block-level atomic + ticket: last block
// finalizes the loss.
__global__ __launch_bounds__(256)
void pair_fin_k(const float* __restrict__ x, const int* __restrict__ row,
                const int* __restrict__ col, const float* __restrict__ t,
                float* __restrict__ acc, unsigned* __restrict__ cnt,
                float* __restrict__ out) {
    const int lane = threadIdx.x & 63;
    const int wave = threadIdx.x >> 6;
    const int p0 = (blockIdx.x * 4 + wave) * 8;

    int rp[8], cp[8];
#pragma unroll
    for (int i = 0; i < 8; ++i) { rp[i] = row[p0 + i]; cp[i] = col[p0 + i]; }
    float4 a[8], b[8];
#pragma unroll
    for (int i = 0; i < 8; ++i) {
        a[i] = *(const float4*)&x[(size_t)rp[i] * D + lane * 4];
        b[i] = *(const float4*)&x[(size_t)cp[i] * D + lane * 4];
    }
    float wsum = 0.0f;
#pragma unroll
    for (int i = 0; i < 8; ++i) {
        float d = fabsf(a[i].x - b[i].x) + fabsf(a[i].y - b[i].y) +
                  fabsf(a[i].z - b[i].z) + fabsf(a[i].w - b[i].w);
#pragma unroll
        for (int off = 32; off > 0; off >>= 1) d += __shfl_xor(d, off, 64);
        if (lane == 0) wsum += d + t[rp[i]];
    }

    __shared__ float bs[4];
    if (lane == 0) bs[wave] = wsum;
    __syncthreads();
    if (threadIdx.x == 0) {
        const float tot = bs[0] + bs[1] + bs[2] + bs[3];
        atomicAdd(acc, tot);
        __threadfence();
        const unsigned tk = atomicAdd(cnt, 1u);
        if (tk == (unsigned)(gridDim.x - 1)) {
            const float v = atomicAdd(acc, 0.0f);  // coherent read
            out[0] = v * (1.0f / (float)NPOS);
        }
    }
}

extern "C" void kernel_launch(void* const* d_in, const int* in_sizes, int n_in,
                              void* d_out, int out_size, void* d_ws, size_t ws_size,
                              hipStream_t stream) {
    const float* x = (const float*)d_in[0];
    const int* row = (const int*)d_in[1];
    const int* col = (const int*)d_in[2];
    float* ws = (float*)d_ws;
    float* out = (float*)d_out;
    unsigned* xqT = (unsigned*)(ws + WS_XQ);
    float* acc = ws + WS_ACC;
    unsigned* cnt = (unsigned*)(ws + WS_CNT);

    cvt_init_k<<<N / 64, 256, 0, stream>>>(x, xqT, acc, cnt);

    dist_tile_k<<<NTRI, 64, 0, stream>>>(xqT, (float2*)(ws + WS_PSTAT));

    row_stats_k<<<N / 4, 256, 0, stream>>>((const float2*)(ws + WS_PSTAT), ws + WS_T);

    pair_fin_k<<<NPOS / 32, 256, 0, stream>>>(x, row, col, ws + WS_T, acc, cnt, out);
}

// Round 7
// 129.402 us; speedup vs baseline: 1.0373x; 1.0373x over previous
//
#include <hip/hip_runtime.h>
#include <math.h>

#define N 4096
#define D 256
#define NPOS 32768
#define TEMP 0.07f
#define INVT (1.0f / 0.07f)
#define BIGF 3.0e38f

#define RQ 5.5f                      // quantization range [-RQ, RQ]
#define QS (255.0f / (2.0f * RQ))    // f32 -> u8 scale
#define DEQ (2.0f * RQ / 255.0f)     // u8-units -> f32

#define NT 64                        // 64x64 tiles per dim
#define NTRI (NT * (NT + 1) / 2)     // 2080 triangle blocks
#define KC 16                        // u32 (k4) per 64-dim chunk

// workspace layout (floats):
// [0 .. 2*N*64)       pstat[r][c] float2 (pmin, psum), r=row, c=64-col-tile
// [.. +1]             loss accumulator (float)
// [.. +1]             ticket counter (uint)
// [WS_XQ ..)          xqT: TRANSPOSED quant matrix, xqT[w][r], w=0..63, r=0..4095
#define WS_PSTAT 0
#define WS_ACC  (2 * N * NT)
#define WS_CNT  (2 * N * NT + 1)
#define WS_XQ   (2 * N * NT + 4)   // 16B-aligned

__device__ __forceinline__ void sad_acc(unsigned a, unsigned b, unsigned& c) {
#if __has_builtin(__builtin_amdgcn_sad_u8)
    c = __builtin_amdgcn_sad_u8(a, b, c);
#else
    asm("v_sad_u8 %0, %1, %2, %0" : "+v"(c) : "v"(a), "v"(b));
#endif
}

// async global->LDS, 16B per lane. LDS dest = uniform base + lane*16.
__device__ __forceinline__ void g2l16(const unsigned* g, unsigned* l) {
    __builtin_amdgcn_global_load_lds(
        (const __attribute__((address_space(1))) unsigned*)g,
        (__attribute__((address_space(3))) unsigned*)l, 16, 0, 0);
}

__device__ __forceinline__ unsigned quant1(float v) {
    const float f = fminf(fmaxf((v + RQ) * QS, 0.0f), 255.0f);
    return (unsigned)__float2uint_rn(f);
}

// Quantize f32 -> packed u8 and store TRANSPOSED: xqT[w][r] (w=word 0..63,
// r=row), which is what lets dist_tile_k stage with global_load_lds
// (linear LDS dest). LDS-transpose: both global sides coalesced;
// [64][65] padding -> conflict-free LDS.
__global__ __launch_bounds__(256)
void cvt_init_k(const float* __restrict__ x, unsigned* __restrict__ xqT,
                float* __restrict__ acc, unsigned* __restrict__ cnt) {
    __shared__ unsigned t[64][65];
    const int r0 = blockIdx.x * 64;     // 64 rows per block
    const int tid = threadIdx.x;
#pragma unroll
    for (int k = 0; k < 16; ++k) {
        const int idx = k * 256 + tid;  // 0..4095 over 64r x 64w
        const int rr = idx >> 6;
        const int w = idx & 63;
        const float4 v = ((const float4*)x)[(size_t)(r0 + rr) * 64 + w];
        t[w][rr] = quant1(v.x) | (quant1(v.y) << 8) |
                   (quant1(v.z) << 16) | (quant1(v.w) << 24);
    }
    __syncthreads();
#pragma unroll
    for (int k = 0; k < 16; ++k) {
        const int idx = k * 256 + tid;
        const int w = idx >> 6;         // wave-uniform per 64-lane group
        const int rr = idx & 63;        // lane -> consecutive r: coalesced
        xqT[(size_t)w * N + r0 + rr] = t[w][rr];
    }
    if (blockIdx.x == 0 && tid == 0) { *acc = 0.0f; *cnt = 0u; }
}

// R6 POST-MORTEM: VGPR stuck at 88 through FIVE scheduling attacks (incl.
// an asm register pin) — the toolchain always re-serializes to
// {reads -> lgkmcnt(0) -> SADs}, and with 2080 one-wave blocks the grid
// caps TLP at ~2 waves/SIMD, so per-wave stalls (~60%) are never covered.
// THIS ROUND pulls the one untouched lever: waves/SIMD.
// SPLIT-K 2-wave blocks: wave w computes the SAME 64x64 tile over dims
// [128w, 128w+128) — 2048 SADs/wave. Each wave has a PRIVATE single-
// buffered 8KB LDS slab: NO barriers in the main loop, only a per-wave
// s_waitcnt vmcnt(0). Block = 16KB LDS -> 10 blocks/CU possible, grid
// gives ~8 -> 16 waves/CU = 4/SIMD (2x anything tried before); stall
// holes filled by TLP instead of (unwinnable) intra-wave scheduling.
// Merge: wave1 dumps uacc into the dead staging LDS (rotation swizzle:
// quarter-wave conflict <= 2-way), wave0 adds and runs the epilogue.
__global__ __launch_bounds__(128)
void dist_tile_k(const unsigned* __restrict__ xqT, float2* __restrict__ pstat) {
    // triangular decode: blockIdx.x -> (bm, bn), bm <= bn
    const int tt = blockIdx.x;
    const int u_ = (NTRI - 1) - tt;
    int r = (int)((sqrtf((float)(8 * u_ + 1)) - 1.0f) * 0.5f);
    while (r * (r + 1) / 2 > u_) --r;
    while ((r + 1) * (r + 2) / 2 <= u_) ++r;
    const int bm = (NT - 1) - r;                      // row tile
    const int bn = (NT - 1) - (u_ - r * (r + 1) / 2); // col tile
    const bool diag = (bm == bn);

    const int tid = threadIdx.x;
    const int lane = tid & 63;
    const int w = tid >> 6;         // K-half: dims [128w, 128w+128)
    const int tx = lane & 7;        // col group: cols tx*8 .. +7
    const int ty = lane >> 3;       // row group: rows ty*8 .. +7

    __shared__ unsigned Sl[4][KC][64];   // 16 KB: [w]=A slab, [2+w]=B slab
    unsigned* Aw = &Sl[w][0][0];
    unsigned* Bw = &Sl[2 + w][0][0];

    unsigned uacc[8][8];  // [i][j]: row ty*8+i, col tx*8+j (partial K)
#pragma unroll
    for (int i = 0; i < 8; ++i)
#pragma unroll
        for (int j = 0; j < 8; ++j) uacc[i][j] = 0u;

    const int rowA0 = bm * 64;
    const int rowB0 = bn * 64;

    // per-lane DMA source: word 32w + 16*c2 + q*4 + (lane>>4), col (lane&15)*4
    const unsigned* gA =
        xqT + (size_t)(32 * w + (lane >> 4)) * N + rowA0 + (lane & 15) * 4;
    const unsigned* gB =
        xqT + (size_t)(32 * w + (lane >> 4)) * N + rowB0 + (lane & 15) * 4;

#pragma unroll
    for (int c2 = 0; c2 < 2; ++c2) {
        const size_t base = (size_t)(16 * c2) * N;
#pragma unroll
        for (int q = 0; q < 4; ++q) {
            g2l16(gA + base + (size_t)q * 4 * N, Aw + q * 256);
            g2l16(gB + base + (size_t)q * 4 * N, Bw + q * 256);
        }
        // per-wave drain; no cross-wave barrier needed (private slabs)
        asm volatile("s_waitcnt vmcnt(0)" ::: "memory");
#pragma unroll
        for (int k4 = 0; k4 < KC; ++k4) {
            const uint4 a0 = *(const uint4*)(Aw + k4 * 64 + ty * 8);
            const uint4 a1 = *(const uint4*)(Aw + k4 * 64 + ty * 8 + 4);
            const uint4 b0 = *(const uint4*)(Bw + k4 * 64 + tx * 8);
            const uint4 b1 = *(const uint4*)(Bw + k4 * 64 + tx * 8 + 4);
            const unsigned av[8] = {a0.x, a0.y, a0.z, a0.w,
                                    a1.x, a1.y, a1.z, a1.w};
            const unsigned bv[8] = {b0.x, b0.y, b0.z, b0.w,
                                    b1.x, b1.y, b1.z, b1.w};
#pragma unroll
            for (int i = 0; i < 8; ++i)
#pragma unroll
                for (int j = 0; j < 8; ++j)
                    sad_acc(av[i], bv[j], uacc[i][j]);
        }
    }

    // ---- cross-wave K-merge through the dead staging LDS ----
    unsigned* mb = &Sl[0][0][0];        // 4096 words = the whole 16 KB
    __syncthreads();                    // both waves done reading slabs
    if (w == 1) {
#pragma unroll
        for (int k = 0; k < 16; ++k) {
            const int i = k >> 1, p = (k & 1) * 4;
            const int slot = (k + lane) & 15;   // rotation: banks spread
            *(uint4*)(mb + lane * 64 + slot * 4) =
                make_uint4(uacc[i][p], uacc[i][p + 1],
                           uacc[i][p + 2], uacc[i][p + 3]);
        }
    }
    __syncthreads();
    if (w == 1) return;                 // no barriers after this point
#pragma unroll
    for (int k = 0; k < 16; ++k) {
        const int i = k >> 1, p = (k & 1) * 4;
        const int slot = (k + lane) & 15;
        const uint4 v = *(const uint4*)(mb + lane * 64 + slot * 4);
        uacc[i][p] += v.x; uacc[i][p + 1] += v.y;
        uacc[i][p + 2] += v.z; uacc[i][p + 3] += v.w;
    }

    // dequantize to float
    float acc[8][8];
#pragma unroll
    for (int i = 0; i < 8; ++i)
#pragma unroll
        for (int j = 0; j < 8; ++j)
            acc[i][j] = (float)uacc[i][j] * DEQ;

    // diagonal exclusion: poison self-distance (min skips it, exp -> 0)
    if (diag) {
#pragma unroll
        for (int i = 0; i < 8; ++i)
#pragma unroll
            for (int j = 0; j < 8; ++j)
                if (ty * 8 + i == tx * 8 + j)   // iff ty==tx && i==j
                    acc[i][j] = BIGF;
    }

    // ---- row stats over all 64 cols: reduce across tx (shfl 1,2,4) ----
#pragma unroll
    for (int i = 0; i < 8; ++i) {
        float mn = BIGF;
#pragma unroll
        for (int j = 0; j < 8; ++j) mn = fminf(mn, acc[i][j]);
        mn = fminf(mn, __shfl_xor(mn, 1, 64));
        mn = fminf(mn, __shfl_xor(mn, 2, 64));
        mn = fminf(mn, __shfl_xor(mn, 4, 64));
        float s = 0.0f;
#pragma unroll
        for (int j = 0; j < 8; ++j)
            s += __expf((mn - acc[i][j]) * INVT);
        s += __shfl_xor(s, 1, 64);
        s += __shfl_xor(s, 2, 64);
        s += __shfl_xor(s, 4, 64);
        if (tx == 0)
            pstat[(size_t)(rowA0 + ty * 8 + i) * NT + bn] = make_float2(mn, s);
    }

    // ---- col stats (iff bm < bn): reduce across ty (shfl 8,16,32) ----
    if (!diag) {
#pragma unroll
        for (int j = 0; j < 8; ++j) {
            float mn = BIGF;
#pragma unroll
            for (int i = 0; i < 8; ++i) mn = fminf(mn, acc[i][j]);
            mn = fminf(mn, __shfl_xor(mn, 8, 64));
            mn = fminf(mn, __shfl_xor(mn, 16, 64));
            mn = fminf(mn, __shfl_xor(mn, 32, 64));
            float s = 0.0f;
#pragma unroll
            for (int i = 0; i < 8; ++i)
                s += __expf((mn - acc[i][j]) * INVT);
            s += __shfl_xor(s, 8, 64);
            s += __shfl_xor(s, 16, 64);
            s += __shfl_xor(s, 32, 64);
            if (ty == 0)
                pstat[(size_t)(rowB0 + tx * 8 + j) * NT + bm] =
                    make_float2(mn, s);
        }
    }
}

// FUSED row_stats + pair gather: per pair, recompute t[r] on the fly from
// pstat (one coalesced float2 read + butterfly reduce — pstat is
// L2-resident, 8x redundancy is ~1us of L2 traffic). Drops one dispatch
// (~8us of launch gap) and the t[] round-trip.
__global__ __launch_bounds__(256)
void pair_fin_k(const float* __restrict__ x, const int* __restrict__ row,
                const int* __restrict__ col, const float2* __restrict__ pstat,
                float* __restrict__ acc, unsigned* __restrict__ cnt,
                float* __restrict__ out) {
    const int lane = threadIdx.x & 63;
    const int wave = threadIdx.x >> 6;
    const int p0 = (blockIdx.x * 4 + wave) * 8;

    int rp[8], cp[8];
#pragma unroll
    for (int i = 0; i < 8; ++i) { rp[i] = row[p0 + i]; cp[i] = col[p0 + i]; }
    float4 a[8], b[8];
#pragma unroll
    for (int i = 0; i < 8; ++i) {
        a[i] = *(const float4*)&x[(size_t)rp[i] * D + lane * 4];
        b[i] = *(const float4*)&x[(size_t)cp[i] * D + lane * 4];
    }
    float wsum = 0.0f;
#pragma unroll
    for (int i = 0; i < 8; ++i) {
        float d = fabsf(a[i].x - b[i].x) + fabsf(a[i].y - b[i].y) +
                  fabsf(a[i].z - b[i].z) + fabsf(a[i].w - b[i].w);
#pragma unroll
        for (int off = 32; off > 0; off >>= 1) d += __shfl_xor(d, off, 64);
        // t[rp[i]] on the fly: lane c holds pstat[rp][c]
        const float2 p = pstat[(size_t)rp[i] * NT + lane];
        float mn = p.x;
#pragma unroll
        for (int off = 32; off > 0; off >>= 1)
            mn = fminf(mn, __shfl_xor(mn, off, 64));
        float s = p.y * __expf((mn - p.x) * INVT);
#pragma unroll
        for (int off = 32; off > 0; off >>= 1) s += __shfl_xor(s, off, 64);
        if (lane == 0) wsum += d + (TEMP * __logf(s) - mn);
    }

    __shared__ float bs[4];
    if (lane == 0) bs[wave] = wsum;
    __syncthreads();
    if (threadIdx.x == 0) {
        const float tot = bs[0] + bs[1] + bs[2] + bs[3];
        atomicAdd(acc, tot);
        __threadfence();
        const unsigned tk = atomicAdd(cnt, 1u);
        if (tk == (unsigned)(gridDim.x - 1)) {
            const float v = atomicAdd(acc, 0.0f);  // coherent read
            out[0] = v * (1.0f / (float)NPOS);
        }
    }
}

extern "C" void kernel_launch(void* const* d_in, const int* in_sizes, int n_in,
                              void* d_out, int out_size, void* d_ws, size_t ws_size,
                              hipStream_t stream) {
    const float* x = (const float*)d_in[0];
    const int* row = (const int*)d_in[1];
    const int* col = (const int*)d_in[2];
    float* ws = (float*)d_ws;
    float* out = (float*)d_out;
    unsigned* xqT = (unsigned*)(ws + WS_XQ);
    float* acc = ws + WS_ACC;
    unsigned* cnt = (unsigned*)(ws + WS_CNT);

    cvt_init_k<<<N / 64, 256, 0, stream>>>(x, xqT, acc, cnt);

    dist_tile_k<<<NTRI, 128, 0, stream>>>(xqT, (float2*)(ws + WS_PSTAT));

    pair_fin_k<<<NPOS / 32, 256, 0, stream>>>(x, row, col,
                                              (const float2*)(ws + WS_PSTAT),
                                              acc, cnt, out);
}